// Round 16
// baseline (127.944 us; speedup 1.0000x reference)
//
#include <hip/hip_runtime.h>
#include <hip/hip_bf16.h>
#include <math.h>

// Problem constants
#define BATCH 2
#define SEQ   2048
#define EMB   1024
#define NH    16
#define HD    64
#define M_ROWS (BATCH * SEQ)   // 4096

typedef __attribute__((ext_vector_type(8))) short bf16x8;
typedef __attribute__((ext_vector_type(4))) float f32x4;

// fp32 -> bf16 round-to-nearest-even, raw bits
__device__ __forceinline__ ushort f2bf(float f) {
    unsigned u = __float_as_uint(f);
    unsigned lsb = (u >> 16) & 1u;
    u += 0x7fffu + lsb;
    return (ushort)(u >> 16);
}

// packed f32 pair -> 2 bf16 in one u32 (RNE), single VALU op
__device__ __forceinline__ unsigned cvt_pk_bf16(float lo, float hi) {
    unsigned r;
    asm("v_cvt_pk_bf16_f32 %0, %1, %2" : "=v"(r) : "v"(lo), "v"(hi));
    return r;
}

__device__ __forceinline__ void gload_lds16(const void* g, void* l) {
    __builtin_amdgcn_global_load_lds(
        (const __attribute__((address_space(1))) unsigned int*)g,
        (__attribute__((address_space(3))) unsigned int*)l, 16, 0, 0);
}

// ---------------------------------------------------------------------------
// fused fp32 -> bf16 conversion of x, qkv_w, o_w (outputs contiguous in ws)
// ---------------------------------------------------------------------------
__global__ __launch_bounds__(256) void cvt3_f32_bf16(
    const float* __restrict__ s1, const float* __restrict__ s2,
    const float* __restrict__ s3, ushort* __restrict__ out,
    int n1, int n2)
{
    int i = (blockIdx.x * 256 + threadIdx.x) * 4;
    const float* src;
    int off;
    if (i < n1)            { src = s1; off = i; }
    else if (i < n1 + n2)  { src = s2; off = i - n1; }
    else                   { src = s3; off = i - n1 - n2; }
    float4 v = *reinterpret_cast<const float4*>(&src[off]);
    uint2 pk;
    pk.x = cvt_pk_bf16(v.x, v.y);
    pk.y = cvt_pk_bf16(v.z, v.w);
    *reinterpret_cast<uint2*>(&out[i]) = pk;
}

// ---------------------------------------------------------------------------
// bf16 MFMA GEMM: C[M,N] = A[M,K] * B[N,K]^T + bias[N]
// MODE 0: fp32 output to Cout (O-projection), direct coalesced stores.
// MODE 1: QKV split. Q cols [0,1024) scaled by BETA; Q/K cols [0,2048) to
//         qkb row-major bf16 via LDS-transpose + coalesced uint4 stores;
//         V cols [2048,3072) TRANSPOSED to vtb[b*16+h][d][t], also via LDS.
// CT (32 KB) aliases Al+Bl — dead after the K-loop's final barrier.
// ---------------------------------------------------------------------------
template <int MODE>
__global__ __launch_bounds__(256) void gemm_mfma_abt(
    const ushort* __restrict__ A, const ushort* __restrict__ B,
    const float* __restrict__ bias, float* __restrict__ Cout,
    ushort* __restrict__ qkb, ushort* __restrict__ vtb,
    int M, int N, int K)
{
    __shared__ ushort LDSbuf[128 * 128];      // 32 KB
    ushort* Al = LDSbuf;                      // [0, 8192)
    ushort* Bl = LDSbuf + 128 * 64;           // [8192, 16384)
    ushort* CT = LDSbuf;                      // epilogue alias (full 16384)

    const int tid  = threadIdx.x;
    const int lane = tid & 63;
    const int wave = tid >> 6;
    const int wr   = wave >> 1;
    const int wc   = wave & 1;
    const int l15  = lane & 15;
    const int l4   = lane >> 4;
    const int m0   = blockIdx.y * 128;
    const int n0   = blockIdx.x * 128;

    f32x4 acc[4][4];
#pragma unroll
    for (int m = 0; m < 4; ++m)
#pragma unroll
        for (int n = 0; n < 4; ++n)
#pragma unroll
            for (int r = 0; r < 4; ++r) acc[m][n][r] = 0.f;

    for (int k0 = 0; k0 < K; k0 += 64) {
#pragma unroll
        for (int it = 0; it < 4; ++it) {
            int chunk = tid + it * 256;
            int row = chunk >> 3;
            int kc  = (chunk & 7) * 8;
            gload_lds16(&A[(size_t)(m0 + row) * K + k0 + kc], &Al[chunk * 8]);
            gload_lds16(&B[(size_t)(n0 + row) * K + k0 + kc], &Bl[chunk * 8]);
        }
        __syncthreads();

#pragma unroll
        for (int kk = 0; kk < 2; ++kk) {
            const int ko = kk * 32 + l4 * 8;
            bf16x8 a[4], b[4];
#pragma unroll
            for (int m = 0; m < 4; ++m)
                a[m] = *reinterpret_cast<const bf16x8*>(
                    &Al[(wr * 64 + m * 16 + l15) * 64 + ko]);
#pragma unroll
            for (int n = 0; n < 4; ++n)
                b[n] = *reinterpret_cast<const bf16x8*>(
                    &Bl[(wc * 64 + n * 16 + l15) * 64 + ko]);
            __builtin_amdgcn_s_setprio(1);
#pragma unroll
            for (int m = 0; m < 4; ++m)
#pragma unroll
                for (int n = 0; n < 4; ++n)
                    acc[m][n] = __builtin_amdgcn_mfma_f32_16x16x32_bf16(
                        a[m], b[n], acc[m][n], 0, 0, 0);
            __builtin_amdgcn_s_setprio(0);
        }
        __syncthreads();   // after last iter: all LDS reads done, CT safe
    }

    // epilogue; C/D: col = lane&15, row = (lane>>4)*4 + reg (verified)
    if (MODE == 0) {
#pragma unroll
        for (int n = 0; n < 4; ++n) {
            const int col = n0 + wc * 64 + n * 16 + l15;
            const float bv = bias[col];
#pragma unroll
            for (int m = 0; m < 4; ++m) {
                const int row0 = m0 + wr * 64 + m * 16 + l4 * 4;
#pragma unroll
                for (int r = 0; r < 4; ++r)
                    Cout[(size_t)(row0 + r) * N + col] = acc[m][n][r] + bv;
            }
        }
    } else if (n0 < 2 * EMB) {
        // ---- Q/K: stage bf16 C-tile to CT row-major (swizzled), then
        //      2048 coalesced 16B stores. Q cols get BETA scale. ----
#pragma unroll
        for (int n = 0; n < 4; ++n) {
            const int Cc = wc * 64 + n * 16 + l15;     // tile-local col
            const int colg = n0 + Cc;
            const float bv = bias[colg];
            const float qs = (colg < EMB) ? 0.18033688f : 1.0f;
#pragma unroll
            for (int m = 0; m < 4; ++m) {
#pragma unroll
                for (int r = 0; r < 4; ++r) {
                    int R = wr * 64 + m * 16 + l4 * 4 + r;
                    CT[R * 128 + (Cc ^ ((R & 7) << 3))] =
                        f2bf((acc[m][n][r] + bv) * qs);
                }
            }
        }
        __syncthreads();
#pragma unroll
        for (int j = 0; j < 8; ++j) {
            int f  = tid + j * 256;          // 0..2047
            int R  = f >> 4;                 // row 0..127
            int c0 = (f & 15) * 8;           // col chunk
            uint4 v = *reinterpret_cast<const uint4*>(
                &CT[R * 128 + (c0 ^ ((R & 7) << 3))]);
            *reinterpret_cast<uint4*>(
                &qkb[(size_t)(m0 + R) * 2048 + n0 + c0]) = v;
        }
    } else {
        // ---- V: stage bf16 C-tile to CT COLUMN-major (swizzled on row idx),
        //      then coalesced 16B stores along t into vtb[bh][d][t]. ----
#pragma unroll
        for (int n = 0; n < 4; ++n) {
            const int Cc = wc * 64 + n * 16 + l15;     // tile-local col (d)
            const float bv = bias[n0 + Cc];
#pragma unroll
            for (int m = 0; m < 4; ++m) {
#pragma unroll
                for (int r = 0; r < 4; ++r) {
                    int R = wr * 64 + m * 16 + l4 * 4 + r;   // tile-local row (t)
                    CT[Cc * 128 + (R ^ ((Cc & 7) << 3))] =
                        f2bf(acc[m][n][r] + bv);
                }
            }
        }
        __syncthreads();
        const int bb = m0 >> 11;             // batch index
        const int tb = m0 & 2047;            // t base within batch
#pragma unroll
        for (int j = 0; j < 8; ++j) {
            int f  = tid + j * 256;          // 0..2047
            int D  = f >> 4;                 // tile-local col (d) 0..127
            int t0 = (f & 15) * 8;           // row (t) chunk
            uint4 v = *reinterpret_cast<const uint4*>(
                &CT[D * 128 + (t0 ^ ((D & 7) << 3))]);
            int dg = (n0 - 2 * EMB) + D;     // global V col 0..1023
            int h  = dg >> 6;
            int dd = dg & 63;
            *reinterpret_cast<uint4*>(
                &vtb[((size_t)(bb * 16 + h) * 64 + dd) * 2048 + tb + t0]) = v;
        }
    }
}

// ---------------------------------------------------------------------------
// MFMA flash attention, swapped-QK softmax. UNIFORM-WORK pair blocks (512
// thr, 8 waves, 1 block/CU; block = (bh, pair p) processing qt=p then 15-p,
// 34 kv-tiles total). Q pre-scaled (log2-domain scores).
// Quad-buffered K/V, 2 tiles per barrier window. Fully-masked-tile skip:
// in the last window, waves 0..3's tile nkv-1 is 100% masked -> skipped.
// Critical-path-lean softmax (per-lane partial max + ballot; l via MFMA-ones).
// ---------------------------------------------------------------------------
__global__ __launch_bounds__(512) void attn_mfma(
    const ushort* __restrict__ qk, const ushort* __restrict__ vt,
    ushort* __restrict__ y)
{
    __shared__ alignas(16) ushort Kl[4][4096];
    __shared__ alignas(16) ushort Vl[4][4096];
    __shared__ alignas(16) ushort QP[8192];     // 128 rows x 64 (Q then P)

    const int tid  = threadIdx.x;
    const int lane = tid & 63;
    const int w    = tid >> 6;     // wave 0..7
    const int l15  = lane & 15;
    const int l4   = lane >> 4;

    // block -> (bh, pair): 4 consecutive bh per XCD
    const int id  = blockIdx.x;                   // 0..255
    const int xcd = id & 7;
    const int bh  = xcd * 4 + ((id >> 3) & 3);    // 0..31
    const int pp  = id >> 5;                      // pair 0..7
    const int b   = bh >> 4;
    const int h   = bh & 15;

    const ushort* qbase = qk + (size_t)b * SEQ * 2048 + h * HD;
    const ushort* kbase = qbase + EMB;
    const ushort* vbase = vt + (size_t)bh * HD * SEQ;        // [d][t]

    const int swz   = (l15 & 7) << 4;
    const int koff0 = ((l4 * 16) ^ swz) >> 1;        // ushort units
    const int koff1 = ((64 + l4 * 16) ^ swz) >> 1;

    int pso[4];
#pragma unroll
    for (int n = 0; n < 4; ++n) pso[n] = ((n * 32 + l4 * 8) ^ swz) >> 1;

    const short OBF = (short)0x3F80;   // 1.0 bf16
    const bf16x8 ones = {OBF, OBF, OBF, OBF, OBF, OBF, OBF, OBF};

    const int qrow = (w * 16 + l15) * 64;    // wave-local Q/P row base

    // staging coordinates (one 16B chunk per thread per 64x64 tile)
    const int sr = tid >> 3;                          // row 0..63
    const int sc = ((tid & 7) ^ (sr & 7)) << 3;       // swizzled col
    const int i2 = tid + 512;
    const int qr2 = i2 >> 3;
    const int qc2 = ((i2 & 7) ^ (qr2 & 7)) << 3;

#pragma unroll
    for (int pass = 0; pass < 2; ++pass) {
        const int qt  = pass ? (15 - pp) : pp;
        const int nkv = 2 * qt + 2;                   // even

        // ---- prologue: stage Q (128x64) + kv tiles 0,1 ----
        gload_lds16(qbase + (size_t)(qt * 128 + sr) * 2048 + sc, &QP[tid * 8]);
        gload_lds16(qbase + (size_t)(qt * 128 + qr2) * 2048 + qc2, &QP[i2 * 8]);
        gload_lds16(kbase + (size_t)sr * 2048 + sc, &Kl[0][tid * 8]);
        gload_lds16(kbase + (size_t)(64 + sr) * 2048 + sc, &Kl[1][tid * 8]);
        gload_lds16(vbase + (size_t)sr * 2048 + sc, &Vl[0][tid * 8]);
        gload_lds16(vbase + (size_t)sr * 2048 + 64 + sc, &Vl[1][tid * 8]);
        __syncthreads();

        const bf16x8 qf0 = *reinterpret_cast<const bf16x8*>(&QP[qrow + koff0]);
        const bf16x8 qf1 = *reinterpret_cast<const bf16x8*>(&QP[qrow + koff1]);

        f32x4 o[4];
#pragma unroll
        for (int n = 0; n < 4; ++n)
#pragma unroll
            for (int r = 0; r < 4; ++r) o[n][r] = 0.f;
        f32x4 lacc = {0.f, 0.f, 0.f, 0.f};
        float m = -3.0e38f;

        const int q0g = qt * 128 + w * 16 + l15;      // causal bound (this lane)

        auto computeTile = [&](const ushort* Kb, const ushort* Vb, int kkt) {
            bf16x8 kf[4][2];
#pragma unroll
            for (int n = 0; n < 4; ++n) {
                kf[n][0] = *reinterpret_cast<const bf16x8*>(
                    &Kb[(n * 16 + l15) * 64 + koff0]);
                kf[n][1] = *reinterpret_cast<const bf16x8*>(
                    &Kb[(n * 16 + l15) * 64 + koff1]);
            }
            f32x4 s[4];
            __builtin_amdgcn_s_setprio(1);
#pragma unroll
            for (int n = 0; n < 4; ++n) {
                f32x4 z = {0.f, 0.f, 0.f, 0.f};
                z = __builtin_amdgcn_mfma_f32_16x16x32_bf16(kf[n][0], qf0, z, 0, 0, 0);
                s[n] = __builtin_amdgcn_mfma_f32_16x16x32_bf16(kf[n][1], qf1, z, 0, 0, 0);
            }
            __builtin_amdgcn_s_setprio(0);

            bf16x8 vf[4][2];
#pragma unroll
            for (int n = 0; n < 4; ++n) {
                vf[n][0] = *reinterpret_cast<const bf16x8*>(
                    &Vb[(n * 16 + l15) * 64 + koff0]);
                vf[n][1] = *reinterpret_cast<const bf16x8*>(
                    &Vb[(n * 16 + l15) * 64 + koff1]);
            }

            // causal mask: only the last two kv tiles can violate causality
            if (kkt >= nkv - 2) {
#pragma unroll
                for (int n = 0; n < 4; ++n)
#pragma unroll
                    for (int r = 0; r < 4; ++r) {
                        int kg = kkt * 64 + n * 16 + l4 * 4 + r;
                        if (kg > q0g) s[n][r] = -3.0e38f;
                    }
            }

            // per-lane partial max (tree); scores already log2-domain
            float a0 = fmaxf(fmaxf(s[0][0], s[0][1]), fmaxf(s[0][2], s[0][3]));
            float a1 = fmaxf(fmaxf(s[1][0], s[1][1]), fmaxf(s[1][2], s[1][3]));
            float a2 = fmaxf(fmaxf(s[2][0], s[2][1]), fmaxf(s[2][2], s[2][3]));
            float a3 = fmaxf(fmaxf(s[3][0], s[3][1]), fmaxf(s[3][2], s[3][3]));
            float pm = fmaxf(fmaxf(a0, a1), fmaxf(a2, a3));

            // defer-max rescale (rare, wave-uniform); ballot covers all (k,q)
            if (__any(pm > m + 8.0f)) {
                float tm = fmaxf(pm, __shfl_xor(pm, 16));
                tm = fmaxf(tm, __shfl_xor(tm, 32));
                float mn = fmaxf(m, tm);
                float al = exp2f(m - mn);
                m = mn;
                float b0 = __shfl(al, l4 * 4 + 0, 16);
                float b1 = __shfl(al, l4 * 4 + 1, 16);
                float b2 = __shfl(al, l4 * 4 + 2, 16);
                float b3 = __shfl(al, l4 * 4 + 3, 16);
                lacc[0] *= b0; lacc[1] *= b1; lacc[2] *= b2; lacc[3] *= b3;
#pragma unroll
                for (int n = 0; n < 4; ++n) {
                    o[n][0] *= b0; o[n][1] *= b1; o[n][2] *= b2; o[n][3] *= b3;
                }
            }

            // p = 2^(s - m), pack + store P (wave-local rows)
#pragma unroll
            for (int n = 0; n < 4; ++n) {
                float pa = exp2f(s[n][0] - m);
                float pb = exp2f(s[n][1] - m);
                float pc = exp2f(s[n][2] - m);
                float pd = exp2f(s[n][3] - m);
                uint2 pk;
                pk.x = cvt_pk_bf16(pa, pb);
                pk.y = cvt_pk_bf16(pc, pd);
                *reinterpret_cast<uint2*>(&QP[qrow + pso[n]]) = pk;
            }

            // O += P V, l += P·1
            bf16x8 pf0 = *reinterpret_cast<const bf16x8*>(&QP[qrow + koff0]);
            bf16x8 pf1 = *reinterpret_cast<const bf16x8*>(&QP[qrow + koff1]);
            __builtin_amdgcn_s_setprio(1);
            lacc = __builtin_amdgcn_mfma_f32_16x16x32_bf16(pf0, ones, lacc, 0, 0, 0);
            lacc = __builtin_amdgcn_mfma_f32_16x16x32_bf16(pf1, ones, lacc, 0, 0, 0);
#pragma unroll
            for (int n = 0; n < 4; ++n) {
                o[n] = __builtin_amdgcn_mfma_f32_16x16x32_bf16(pf0, vf[n][0], o[n], 0, 0, 0);
                o[n] = __builtin_amdgcn_mfma_f32_16x16x32_bf16(pf1, vf[n][1], o[n], 0, 0, 0);
            }
            __builtin_amdgcn_s_setprio(0);
        };

        // ---- main loop: 2 tiles per barrier window ----
        for (int kk = 0; kk < nkv; kk += 2) {
            if (kk + 2 < nkv) {
                const int b2 = (kk + 2) & 3;
                const int b3 = (kk + 3) & 3;
                gload_lds16(kbase + (size_t)((kk + 2) * 64 + sr) * 2048 + sc,
                            &Kl[b2][tid * 8]);
                gload_lds16(kbase + (size_t)((kk + 3) * 64 + sr) * 2048 + sc,
                            &Kl[b3][tid * 8]);
                gload_lds16(vbase + (size_t)sr * 2048 + (kk + 2) * 64 + sc,
                            &Vl[b2][tid * 8]);
                gload_lds16(vbase + (size_t)sr * 2048 + (kk + 3) * 64 + sc,
                            &Vl[b3][tid * 8]);
            }
            computeTile(Kl[kk & 3], Vl[kk & 3], kk);
            // tile nkv-1 is fully masked for waves 0..3 (kv_start = 128qt+64
            // > q_max = 128qt + 16w + 15 when w < 4) -> skip entirely.
            if (!(kk == nkv - 2 && w < 4))
                computeTile(Kl[(kk + 1) & 3], Vl[(kk + 1) & 3], kk + 1);
            __syncthreads();
        }

        // epilogue: O rows q = w*16 + l4*4 + r, cols d = n*16 + l15
#pragma unroll
        for (int r = 0; r < 4; ++r) {
            float inv = 1.f / lacc[r];
            int row = qt * 128 + w * 16 + l4 * 4 + r;
#pragma unroll
            for (int n = 0; n < 4; ++n) {
                y[(size_t)(b * SEQ + row) * EMB + h * HD + n * 16 + l15] =
                    f2bf(o[n][r] * inv);
            }
        }
        __syncthreads();   // LDS safe before next pass's prologue
    }
}

// ---------------------------------------------------------------------------
extern "C" void kernel_launch(void* const* d_in, const int* in_sizes, int n_in,
                              void* d_out, int out_size, void* d_ws, size_t ws_size,
                              hipStream_t stream)
{
    const float* x     = (const float*)d_in[0];   // [B,T,E]
    const float* qkv_w = (const float*)d_in[1];   // [3E,E]
    const float* qkv_b = (const float*)d_in[2];   // [3E]
    const float* o_w   = (const float*)d_in[3];   // [E,E]
    const float* o_b   = (const float*)d_in[4];   // [E]
    float* out = (float*)d_out;                   // [B,T,E] fp32

    // workspace (ushort units)
    ushort* xb    = (ushort*)d_ws;                       // 4M
    ushort* wqkvb = xb    + (size_t)M_ROWS * EMB;        // 3M
    ushort* owb   = wqkvb + (size_t)3 * EMB * EMB;       // 1M
    ushort* qkb   = owb   + (size_t)EMB * EMB;           // 8M  [4096][2048]
    ushort* vtb   = qkb   + (size_t)M_ROWS * 2 * EMB;    // 4M  [32][64][2048]
    ushort* ybb   = vtb   + (size_t)32 * HD * SEQ;       // 4M  [4096][1024]

    // 0) fused fp32 -> bf16 (x, qkv_w, o_w -> contiguous xb/wqkvb/owb)
    {
        int n1 = M_ROWS * EMB;        // 4M
        int n2 = 3 * EMB * EMB;       // 3M
        int ntot = n1 + n2 + EMB * EMB;
        cvt3_f32_bf16<<<ntot / 1024, 256, 0, stream>>>(
            x, qkv_w, o_w, xb, n1, n2);
    }

    // 1) QKV projection, split output: Q (BETA-scaled)/K row-major, V transposed
    {
        dim3 grid(3 * EMB / 128, M_ROWS / 128);   // (24, 32)
        gemm_mfma_abt<1><<<grid, 256, 0, stream>>>(
            xb, wqkvb, qkv_b, nullptr, qkb, vtb, M_ROWS, 3 * EMB, EMB);
    }

    // 2) MFMA flash attention -> ybb (bf16 [M,E]); uniform-work pair blocks
    {
        attn_mfma<<<256, 512, 0, stream>>>(qkb, vtb, ybb);
    }

    // 3) Output projection (fp32 out)
    {
        dim3 grid(EMB / 128, M_ROWS / 128);       // (8, 32)
        gemm_mfma_abt<0><<<grid, 256, 0, stream>>>(
            ybb, owb, o_b, out, nullptr, nullptr, M_ROWS, EMB, EMB);
    }
}

// Round 17
// 119.028 us; speedup vs baseline: 1.0749x; 1.0749x over previous
//
#include <hip/hip_runtime.h>
#include <hip/hip_bf16.h>
#include <math.h>

// Problem constants
#define BATCH 2
#define SEQ   2048
#define EMB   1024
#define NH    16
#define HD    64
#define M_ROWS (BATCH * SEQ)   // 4096

typedef __attribute__((ext_vector_type(8))) short bf16x8;
typedef __attribute__((ext_vector_type(4))) float f32x4;

// fp32 -> bf16 round-to-nearest-even, raw bits
__device__ __forceinline__ ushort f2bf(float f) {
    unsigned u = __float_as_uint(f);
    unsigned lsb = (u >> 16) & 1u;
    u += 0x7fffu + lsb;
    return (ushort)(u >> 16);
}

// packed f32 pair -> 2 bf16 in one u32 (RNE), single VALU op
__device__ __forceinline__ unsigned cvt_pk_bf16(float lo, float hi) {
    unsigned r;
    asm("v_cvt_pk_bf16_f32 %0, %1, %2" : "=v"(r) : "v"(lo), "v"(hi));
    return r;
}

__device__ __forceinline__ void gload_lds16(const void* g, void* l) {
    __builtin_amdgcn_global_load_lds(
        (const __attribute__((address_space(1))) unsigned int*)g,
        (__attribute__((address_space(3))) unsigned int*)l, 16, 0, 0);
}

// ---------------------------------------------------------------------------
// fused fp32 -> bf16 conversion of x, qkv_w, o_w (outputs contiguous in ws)
// ---------------------------------------------------------------------------
__global__ __launch_bounds__(256) void cvt3_f32_bf16(
    const float* __restrict__ s1, const float* __restrict__ s2,
    const float* __restrict__ s3, ushort* __restrict__ out,
    int n1, int n2)
{
    int i = (blockIdx.x * 256 + threadIdx.x) * 4;
    const float* src;
    int off;
    if (i < n1)            { src = s1; off = i; }
    else if (i < n1 + n2)  { src = s2; off = i - n1; }
    else                   { src = s3; off = i - n1 - n2; }
    float4 v = *reinterpret_cast<const float4*>(&src[off]);
    uint2 pk;
    pk.x = cvt_pk_bf16(v.x, v.y);
    pk.y = cvt_pk_bf16(v.z, v.w);
    *reinterpret_cast<uint2*>(&out[i]) = pk;
}

// ---------------------------------------------------------------------------
// bf16 MFMA GEMM: C[M,N] = A[M,K] * B[N,K]^T + bias[N]
// MODE 0: fp32 output to Cout (O-projection).
// MODE 1: QKV split — cols [0,1024) = Q, scaled by BETA=0.125*log2(e);
//         cols [0,2048) bf16 to qkb (stride 2048), direct stores;
//         cols [2048,3072) = V written TRANSPOSED to vtb[b*16+h][d][t].
// ---------------------------------------------------------------------------
template <int MODE>
__global__ __launch_bounds__(256) void gemm_mfma_abt(
    const ushort* __restrict__ A, const ushort* __restrict__ B,
    const float* __restrict__ bias, float* __restrict__ Cout,
    ushort* __restrict__ qkb, ushort* __restrict__ vtb,
    int M, int N, int K)
{
    __shared__ ushort Al[128 * 64];
    __shared__ ushort Bl[128 * 64];

    const int tid  = threadIdx.x;
    const int lane = tid & 63;
    const int wave = tid >> 6;
    const int wr   = wave >> 1;
    const int wc   = wave & 1;
    const int l15  = lane & 15;
    const int l4   = lane >> 4;
    const int m0   = blockIdx.y * 128;
    const int n0   = blockIdx.x * 128;

    f32x4 acc[4][4];
#pragma unroll
    for (int m = 0; m < 4; ++m)
#pragma unroll
        for (int n = 0; n < 4; ++n)
#pragma unroll
            for (int r = 0; r < 4; ++r) acc[m][n][r] = 0.f;

    for (int k0 = 0; k0 < K; k0 += 64) {
#pragma unroll
        for (int it = 0; it < 4; ++it) {
            int chunk = tid + it * 256;
            int row = chunk >> 3;
            int kc  = (chunk & 7) * 8;
            gload_lds16(&A[(size_t)(m0 + row) * K + k0 + kc], &Al[chunk * 8]);
            gload_lds16(&B[(size_t)(n0 + row) * K + k0 + kc], &Bl[chunk * 8]);
        }
        __syncthreads();

#pragma unroll
        for (int kk = 0; kk < 2; ++kk) {
            const int ko = kk * 32 + l4 * 8;
            bf16x8 a[4], b[4];
#pragma unroll
            for (int m = 0; m < 4; ++m)
                a[m] = *reinterpret_cast<const bf16x8*>(
                    &Al[(wr * 64 + m * 16 + l15) * 64 + ko]);
#pragma unroll
            for (int n = 0; n < 4; ++n)
                b[n] = *reinterpret_cast<const bf16x8*>(
                    &Bl[(wc * 64 + n * 16 + l15) * 64 + ko]);
            __builtin_amdgcn_s_setprio(1);
#pragma unroll
            for (int m = 0; m < 4; ++m)
#pragma unroll
                for (int n = 0; n < 4; ++n)
                    acc[m][n] = __builtin_amdgcn_mfma_f32_16x16x32_bf16(
                        a[m], b[n], acc[m][n], 0, 0, 0);
            __builtin_amdgcn_s_setprio(0);
        }
        __syncthreads();
    }

    // epilogue; C/D: col = lane&15, row = (lane>>4)*4 + reg (verified)
#pragma unroll
    for (int n = 0; n < 4; ++n) {
        const int col = n0 + wc * 64 + n * 16 + l15;
        const float bv = bias[col];
        if (MODE == 0) {
#pragma unroll
            for (int m = 0; m < 4; ++m) {
                const int row0 = m0 + wr * 64 + m * 16 + l4 * 4;
#pragma unroll
                for (int r = 0; r < 4; ++r)
                    Cout[(size_t)(row0 + r) * N + col] = acc[m][n][r] + bv;
            }
        } else if (col < 2 * EMB) {
            // Q/K part, row-major bf16, stride 2048. Q pre-scaled by BETA.
            const float qs = (col < EMB) ? 0.18033688f : 1.0f;
#pragma unroll
            for (int m = 0; m < 4; ++m) {
                const int row0 = m0 + wr * 64 + m * 16 + l4 * 4;
#pragma unroll
                for (int r = 0; r < 4; ++r)
                    qkb[(size_t)(row0 + r) * 2048 + col] =
                        f2bf((acc[m][n][r] + bv) * qs);
            }
        } else {
            // V part, transposed: vtb[(b*16+h)*64 + d][t], t = row
            const int h = (col - 2 * EMB) >> 6;
            const int d = col & 63;
#pragma unroll
            for (int m = 0; m < 4; ++m) {
                const int row0 = m0 + wr * 64 + m * 16 + l4 * 4;
                const int bb = row0 >> 11;
                const int t  = row0 & 2047;
                uint2 pk;
                pk.x = cvt_pk_bf16(acc[m][n][0] + bv, acc[m][n][1] + bv);
                pk.y = cvt_pk_bf16(acc[m][n][2] + bv, acc[m][n][3] + bv);
                *reinterpret_cast<uint2*>(
                    &vtb[((size_t)(bb * 16 + h) * 64 + d) * 2048 + t]) = pk;
            }
        }
    }
}

// ---------------------------------------------------------------------------
// MFMA flash attention, swapped-QK softmax. PAIR-PARALLEL blocks:
// 512 thr (8 waves), block = (bh, pp). Waves 0..3 own q-tile qtA=pp
// (32 q-rows each, two independent 16-row subblocks); waves 4..7 own
// qtB=15-pp. ONE kv stream 0..nkvB-1 (nkvB >= nkvA); A-waves skip compute
// past nkvA (wave-uniform). K/V fragments shared across both subblocks
// (DS per unit work halved); independent softmax states (m0/m1) give
// in-wave ILP. Quad-buffered K/V, 2 tiles per barrier window.
// Q pre-scaled by BETA (log2-domain scores); lean softmax (per-lane
// partial max + ballot; l via MFMA-ones).
// ---------------------------------------------------------------------------
__global__ __launch_bounds__(512) void attn_mfma(
    const ushort* __restrict__ qk, const ushort* __restrict__ vt,
    ushort* __restrict__ y)
{
    __shared__ alignas(16) ushort Kl[4][4096];
    __shared__ alignas(16) ushort Vl[4][4096];
    __shared__ alignas(16) ushort QP[16384];    // 256 rows x 64 (Q -> P, wave-private)

    const int tid  = threadIdx.x;
    const int lane = tid & 63;
    const int w    = tid >> 6;     // wave 0..7
    const int u    = w & 3;        // wave within group
    const int wg   = w >> 2;       // 0: tile A (qt=pp), 1: tile B (qt=15-pp)
    const int l15  = lane & 15;
    const int l4   = lane >> 4;

    // block -> (bh, pp): 4 consecutive bh per XCD
    const int id  = blockIdx.x;                   // 0..255
    const int xcd = id & 7;
    const int bh  = xcd * 4 + ((id >> 3) & 3);    // 0..31
    const int pp  = id >> 5;                      // 0..7
    const int b   = bh >> 4;
    const int h   = bh & 15;

    const int qtX  = wg ? (15 - pp) : pp;
    const int nkvX = 2 * qtX + 2;                 // this group's kv range
    const int nkvM = 32 - 2 * pp;                 // block's max (B group)

    const ushort* qbase = qk + (size_t)b * SEQ * 2048 + h * HD;
    const ushort* kbase = qbase + EMB;
    const ushort* vbase = vt + (size_t)bh * HD * SEQ;        // [d][t]

    const int swz   = (l15 & 7) << 4;
    const int koff0 = ((l4 * 16) ^ swz) >> 1;        // ushort units
    const int koff1 = ((64 + l4 * 16) ^ swz) >> 1;
    int pso[4];
#pragma unroll
    for (int n = 0; n < 4; ++n) pso[n] = ((n * 32 + l4 * 8) ^ swz) >> 1;

    const short OBF = (short)0x3F80;   // 1.0 bf16
    const bf16x8 ones = {OBF, OBF, OBF, OBF, OBF, OBF, OBF, OBF};

    // wave-private Q/P rows: [wg*128 + u*32, +32)
    const int qrow0 = (wg * 128 + u * 32 + l15) * 64;
    const int qrow1 = qrow0 + 16 * 64;

    // staging coordinates (one 16B chunk per thread per 64x64 tile)
    const int sr = tid >> 3;                          // row 0..63
    const int sc = ((tid & 7) ^ (sr & 7)) << 3;       // swizzled col

    // ---- prologue: stage Q (256 rows: A tile then B tile) + kv tiles 0,1 ----
#pragma unroll
    for (int it = 0; it < 4; ++it) {
        int c = tid + it * 512;              // 0..2047
        int r256 = c >> 3;                   // 0..255
        int cc = ((c & 7) ^ (r256 & 7)) << 3;
        int grow = ((r256 >> 7) ? (15 - pp) : pp) * 128 + (r256 & 127);
        gload_lds16(qbase + (size_t)grow * 2048 + cc, &QP[c * 8]);
    }
    gload_lds16(kbase + (size_t)sr * 2048 + sc, &Kl[0][tid * 8]);
    gload_lds16(kbase + (size_t)(64 + sr) * 2048 + sc, &Kl[1][tid * 8]);
    gload_lds16(vbase + (size_t)sr * 2048 + sc, &Vl[0][tid * 8]);
    gload_lds16(vbase + (size_t)sr * 2048 + 64 + sc, &Vl[1][tid * 8]);
    __syncthreads();

    // Q fragments (wave reads ONLY its own rows; P later overwrites same rows)
    const bf16x8 qf00 = *reinterpret_cast<const bf16x8*>(&QP[qrow0 + koff0]);
    const bf16x8 qf01 = *reinterpret_cast<const bf16x8*>(&QP[qrow0 + koff1]);
    const bf16x8 qf10 = *reinterpret_cast<const bf16x8*>(&QP[qrow1 + koff0]);
    const bf16x8 qf11 = *reinterpret_cast<const bf16x8*>(&QP[qrow1 + koff1]);

    f32x4 o0[4], o1[4];
#pragma unroll
    for (int n = 0; n < 4; ++n)
#pragma unroll
        for (int r = 0; r < 4; ++r) { o0[n][r] = 0.f; o1[n][r] = 0.f; }
    f32x4 lacc0 = {0.f, 0.f, 0.f, 0.f};
    f32x4 lacc1 = {0.f, 0.f, 0.f, 0.f};
    float m0 = -3.0e38f, m1 = -3.0e38f;

    const int q0g = qtX * 128 + u * 32 + l15;   // causal bounds (subblock 0/1)
    const int q1g = q0g + 16;

    auto computeTile = [&](const ushort* Kb, const ushort* Vb, int kkt) {
        bf16x8 kf[4][2];
#pragma unroll
        for (int n = 0; n < 4; ++n) {
            kf[n][0] = *reinterpret_cast<const bf16x8*>(
                &Kb[(n * 16 + l15) * 64 + koff0]);
            kf[n][1] = *reinterpret_cast<const bf16x8*>(
                &Kb[(n * 16 + l15) * 64 + koff1]);
        }
        f32x4 s0[4], s1[4];
        __builtin_amdgcn_s_setprio(1);
#pragma unroll
        for (int n = 0; n < 4; ++n) {
            f32x4 z0 = {0.f, 0.f, 0.f, 0.f};
            z0 = __builtin_amdgcn_mfma_f32_16x16x32_bf16(kf[n][0], qf00, z0, 0, 0, 0);
            s0[n] = __builtin_amdgcn_mfma_f32_16x16x32_bf16(kf[n][1], qf01, z0, 0, 0, 0);
            f32x4 z1 = {0.f, 0.f, 0.f, 0.f};
            z1 = __builtin_amdgcn_mfma_f32_16x16x32_bf16(kf[n][0], qf10, z1, 0, 0, 0);
            s1[n] = __builtin_amdgcn_mfma_f32_16x16x32_bf16(kf[n][1], qf11, z1, 0, 0, 0);
        }
        __builtin_amdgcn_s_setprio(0);

        bf16x8 vf[4][2];
#pragma unroll
        for (int n = 0; n < 4; ++n) {
            vf[n][0] = *reinterpret_cast<const bf16x8*>(
                &Vb[(n * 16 + l15) * 64 + koff0]);
            vf[n][1] = *reinterpret_cast<const bf16x8*>(
                &Vb[(n * 16 + l15) * 64 + koff1]);
        }

        // causal mask: only this group's last two kv tiles can violate
        if (kkt >= nkvX - 2) {
#pragma unroll
            for (int n = 0; n < 4; ++n)
#pragma unroll
                for (int r = 0; r < 4; ++r) {
                    int kg = kkt * 64 + n * 16 + l4 * 4 + r;
                    if (kg > q0g) s0[n][r] = -3.0e38f;
                    if (kg > q1g) s1[n][r] = -3.0e38f;
                }
        }

        // per-lane partial max trees (scores already log2-domain)
        float pa0 = fmaxf(fmaxf(s0[0][0], s0[0][1]), fmaxf(s0[0][2], s0[0][3]));
        float pa1 = fmaxf(fmaxf(s0[1][0], s0[1][1]), fmaxf(s0[1][2], s0[1][3]));
        float pa2 = fmaxf(fmaxf(s0[2][0], s0[2][1]), fmaxf(s0[2][2], s0[2][3]));
        float pa3 = fmaxf(fmaxf(s0[3][0], s0[3][1]), fmaxf(s0[3][2], s0[3][3]));
        float pm0 = fmaxf(fmaxf(pa0, pa1), fmaxf(pa2, pa3));
        float pb0 = fmaxf(fmaxf(s1[0][0], s1[0][1]), fmaxf(s1[0][2], s1[0][3]));
        float pb1 = fmaxf(fmaxf(s1[1][0], s1[1][1]), fmaxf(s1[1][2], s1[1][3]));
        float pb2 = fmaxf(fmaxf(s1[2][0], s1[2][1]), fmaxf(s1[2][2], s1[2][3]));
        float pb3 = fmaxf(fmaxf(s1[3][0], s1[3][1]), fmaxf(s1[3][2], s1[3][3]));
        float pm1 = fmaxf(fmaxf(pb0, pb1), fmaxf(pb2, pb3));

        // defer-max rescale (rare, wave-uniform); ballot covers all (k,q)
        if (__any((pm0 > m0 + 8.0f) || (pm1 > m1 + 8.0f))) {
            float tm0 = fmaxf(pm0, __shfl_xor(pm0, 16));
            tm0 = fmaxf(tm0, __shfl_xor(tm0, 32));
            float tm1 = fmaxf(pm1, __shfl_xor(pm1, 16));
            tm1 = fmaxf(tm1, __shfl_xor(tm1, 32));
            float mn0 = fmaxf(m0, tm0);
            float al0 = exp2f(m0 - mn0);
            m0 = mn0;
            float mn1 = fmaxf(m1, tm1);
            float al1 = exp2f(m1 - mn1);
            m1 = mn1;
            float a00 = __shfl(al0, l4 * 4 + 0, 16);
            float a01 = __shfl(al0, l4 * 4 + 1, 16);
            float a02 = __shfl(al0, l4 * 4 + 2, 16);
            float a03 = __shfl(al0, l4 * 4 + 3, 16);
            float a10 = __shfl(al1, l4 * 4 + 0, 16);
            float a11 = __shfl(al1, l4 * 4 + 1, 16);
            float a12 = __shfl(al1, l4 * 4 + 2, 16);
            float a13 = __shfl(al1, l4 * 4 + 3, 16);
            lacc0[0] *= a00; lacc0[1] *= a01; lacc0[2] *= a02; lacc0[3] *= a03;
            lacc1[0] *= a10; lacc1[1] *= a11; lacc1[2] *= a12; lacc1[3] *= a13;
#pragma unroll
            for (int n = 0; n < 4; ++n) {
                o0[n][0] *= a00; o0[n][1] *= a01; o0[n][2] *= a02; o0[n][3] *= a03;
                o1[n][0] *= a10; o1[n][1] *= a11; o1[n][2] *= a12; o1[n][3] *= a13;
            }
        }

        // p = 2^(s - m), pack + store P (two independent chains)
#pragma unroll
        for (int n = 0; n < 4; ++n) {
            float pa = exp2f(s0[n][0] - m0);
            float pb = exp2f(s0[n][1] - m0);
            float pc = exp2f(s0[n][2] - m0);
            float pd = exp2f(s0[n][3] - m0);
            uint2 pk;
            pk.x = cvt_pk_bf16(pa, pb);
            pk.y = cvt_pk_bf16(pc, pd);
            *reinterpret_cast<uint2*>(&QP[qrow0 + pso[n]]) = pk;
            pa = exp2f(s1[n][0] - m1);
            pb = exp2f(s1[n][1] - m1);
            pc = exp2f(s1[n][2] - m1);
            pd = exp2f(s1[n][3] - m1);
            pk.x = cvt_pk_bf16(pa, pb);
            pk.y = cvt_pk_bf16(pc, pd);
            *reinterpret_cast<uint2*>(&QP[qrow1 + pso[n]]) = pk;
        }

        // O += P V, l += P·1 (V frags shared by both subblocks)
        bf16x8 pf00 = *reinterpret_cast<const bf16x8*>(&QP[qrow0 + koff0]);
        bf16x8 pf01 = *reinterpret_cast<const bf16x8*>(&QP[qrow0 + koff1]);
        bf16x8 pf10 = *reinterpret_cast<const bf16x8*>(&QP[qrow1 + koff0]);
        bf16x8 pf11 = *reinterpret_cast<const bf16x8*>(&QP[qrow1 + koff1]);
        __builtin_amdgcn_s_setprio(1);
        lacc0 = __builtin_amdgcn_mfma_f32_16x16x32_bf16(pf00, ones, lacc0, 0, 0, 0);
        lacc0 = __builtin_amdgcn_mfma_f32_16x16x32_bf16(pf01, ones, lacc0, 0, 0, 0);
        lacc1 = __builtin_amdgcn_mfma_f32_16x16x32_bf16(pf10, ones, lacc1, 0, 0, 0);
        lacc1 = __builtin_amdgcn_mfma_f32_16x16x32_bf16(pf11, ones, lacc1, 0, 0, 0);
#pragma unroll
        for (int n = 0; n < 4; ++n) {
            o0[n] = __builtin_amdgcn_mfma_f32_16x16x32_bf16(pf00, vf[n][0], o0[n], 0, 0, 0);
            o0[n] = __builtin_amdgcn_mfma_f32_16x16x32_bf16(pf01, vf[n][1], o0[n], 0, 0, 0);
            o1[n] = __builtin_amdgcn_mfma_f32_16x16x32_bf16(pf10, vf[n][0], o1[n], 0, 0, 0);
            o1[n] = __builtin_amdgcn_mfma_f32_16x16x32_bf16(pf11, vf[n][1], o1[n], 0, 0, 0);
        }
        __builtin_amdgcn_s_setprio(0);
    };

    auto doTile = [&](int t) {
        if (t >= nkvX) return;                 // A-waves past their range
        if (t == nkvX - 1 && u < 2) return;    // fully-masked tile for low waves
        computeTile(Kl[t & 3], Vl[t & 3], t);
    };

    // ---- main loop: 2 tiles per barrier window over the block's max range ----
    for (int kk = 0; kk < nkvM; kk += 2) {
        if (kk + 2 < nkvM) {
            const int b2 = (kk + 2) & 3;
            const int b3 = (kk + 3) & 3;
            gload_lds16(kbase + (size_t)((kk + 2) * 64 + sr) * 2048 + sc,
                        &Kl[b2][tid * 8]);
            gload_lds16(kbase + (size_t)((kk + 3) * 64 + sr) * 2048 + sc,
                        &Kl[b3][tid * 8]);
            gload_lds16(vbase + (size_t)sr * 2048 + (kk + 2) * 64 + sc,
                        &Vl[b2][tid * 8]);
            gload_lds16(vbase + (size_t)sr * 2048 + (kk + 3) * 64 + sc,
                        &Vl[b3][tid * 8]);
        }
        doTile(kk);
        doTile(kk + 1);
        __syncthreads();
    }

    // epilogue: subblock 0 rows qtX*128+u*32+l4*4+r, subblock 1 +16
#pragma unroll
    for (int r = 0; r < 4; ++r) {
        float inv0 = 1.f / lacc0[r];
        float inv1 = 1.f / lacc1[r];
        int row0 = qtX * 128 + u * 32 + l4 * 4 + r;
        int row1 = row0 + 16;
#pragma unroll
        for (int n = 0; n < 4; ++n) {
            y[(size_t)(b * SEQ + row0) * EMB + h * HD + n * 16 + l15] =
                f2bf(o0[n][r] * inv0);
            y[(size_t)(b * SEQ + row1) * EMB + h * HD + n * 16 + l15] =
                f2bf(o1[n][r] * inv1);
        }
    }
}

// ---------------------------------------------------------------------------
extern "C" void kernel_launch(void* const* d_in, const int* in_sizes, int n_in,
                              void* d_out, int out_size, void* d_ws, size_t ws_size,
                              hipStream_t stream)
{
    const float* x     = (const float*)d_in[0];   // [B,T,E]
    const float* qkv_w = (const float*)d_in[1];   // [3E,E]
    const float* qkv_b = (const float*)d_in[2];   // [3E]
    const float* o_w   = (const float*)d_in[3];   // [E,E]
    const float* o_b   = (const float*)d_in[4];   // [E]
    float* out = (float*)d_out;                   // [B,T,E] fp32

    // workspace (ushort units)
    ushort* xb    = (ushort*)d_ws;                       // 4M
    ushort* wqkvb = xb    + (size_t)M_ROWS * EMB;        // 3M
    ushort* owb   = wqkvb + (size_t)3 * EMB * EMB;       // 1M
    ushort* qkb   = owb   + (size_t)EMB * EMB;           // 8M  [4096][2048]
    ushort* vtb   = qkb   + (size_t)M_ROWS * 2 * EMB;    // 4M  [32][64][2048]
    ushort* ybb   = vtb   + (size_t)32 * HD * SEQ;       // 4M  [4096][1024]

    // 0) fused fp32 -> bf16 (x, qkv_w, o_w -> contiguous xb/wqkvb/owb)
    {
        int n1 = M_ROWS * EMB;        // 4M
        int n2 = 3 * EMB * EMB;       // 3M
        int ntot = n1 + n2 + EMB * EMB;
        cvt3_f32_bf16<<<ntot / 1024, 256, 0, stream>>>(
            x, qkv_w, o_w, xb, n1, n2);
    }

    // 1) QKV projection, split output: Q (BETA-scaled)/K row-major, V transposed
    {
        dim3 grid(3 * EMB / 128, M_ROWS / 128);   // (24, 32)
        gemm_mfma_abt<1><<<grid, 256, 0, stream>>>(
            xb, wqkvb, qkv_b, nullptr, qkb, vtb, M_ROWS, 3 * EMB, EMB);
    }

    // 2) MFMA flash attention -> ybb (bf16 [M,E]); pair-parallel blocks
    {
        attn_mfma<<<256, 512, 0, stream>>>(qkb, vtb, ybb);
    }

    // 3) Output projection (fp32 out)
    {
        dim3 grid(EMB / 128, M_ROWS / 128);       // (8, 32)
        gemm_mfma_abt<0><<<grid, 256, 0, stream>>>(
            ybb, owb, o_b, out, nullptr, nullptr, M_ROWS, EMB, EMB);
    }
}

// Round 18
// 115.917 us; speedup vs baseline: 1.1038x; 1.0268x over previous
//
#include <hip/hip_runtime.h>
#include <hip/hip_bf16.h>
#include <math.h>

// Problem constants
#define BATCH 2
#define SEQ   2048
#define EMB   1024
#define NH    16
#define HD    64
#define M_ROWS (BATCH * SEQ)   // 4096

typedef __attribute__((ext_vector_type(8))) short bf16x8;
typedef __attribute__((ext_vector_type(4))) float f32x4;

// fp32 -> bf16 round-to-nearest-even, raw bits
__device__ __forceinline__ ushort f2bf(float f) {
    unsigned u = __float_as_uint(f);
    unsigned lsb = (u >> 16) & 1u;
    u += 0x7fffu + lsb;
    return (ushort)(u >> 16);
}

// packed f32 pair -> 2 bf16 in one u32 (RNE), single VALU op
__device__ __forceinline__ unsigned cvt_pk_bf16(float lo, float hi) {
    unsigned r;
    asm("v_cvt_pk_bf16_f32 %0, %1, %2" : "=v"(r) : "v"(lo), "v"(hi));
    return r;
}

__device__ __forceinline__ void gload_lds16(const void* g, void* l) {
    __builtin_amdgcn_global_load_lds(
        (const __attribute__((address_space(1))) unsigned int*)g,
        (__attribute__((address_space(3))) unsigned int*)l, 16, 0, 0);
}

// ---------------------------------------------------------------------------
// fused fp32 -> bf16 conversion of x, qkv_w, o_w (outputs contiguous in ws)
// ---------------------------------------------------------------------------
__global__ __launch_bounds__(256) void cvt3_f32_bf16(
    const float* __restrict__ s1, const float* __restrict__ s2,
    const float* __restrict__ s3, ushort* __restrict__ out,
    int n1, int n2)
{
    int i = (blockIdx.x * 256 + threadIdx.x) * 4;
    const float* src;
    int off;
    if (i < n1)            { src = s1; off = i; }
    else if (i < n1 + n2)  { src = s2; off = i - n1; }
    else                   { src = s3; off = i - n1 - n2; }
    float4 v = *reinterpret_cast<const float4*>(&src[off]);
    uint2 pk;
    pk.x = cvt_pk_bf16(v.x, v.y);
    pk.y = cvt_pk_bf16(v.z, v.w);
    *reinterpret_cast<uint2*>(&out[i]) = pk;
}

// ---------------------------------------------------------------------------
// bf16 MFMA GEMM: C[M,N] = A[M,K] * B[N,K]^T + bias[N]
// 1-D grid with XCD-chunked swizzle (T1): f = (id&7)*chunk + (id>>3),
// N-major order -> each XCD keeps a few B-panels L2-resident.
// MODE 0: fp32 output to Cout (O-projection).
// MODE 1: QKV split — cols [0,1024) = Q, scaled by BETA=0.125*log2(e);
//         cols [0,2048) bf16 to qkb (stride 2048), direct stores;
//         cols [2048,3072) = V written TRANSPOSED to vtb[b*16+h][d][t].
// ---------------------------------------------------------------------------
template <int MODE>
__global__ __launch_bounds__(256) void gemm_mfma_abt(
    const ushort* __restrict__ A, const ushort* __restrict__ B,
    const float* __restrict__ bias, float* __restrict__ Cout,
    ushort* __restrict__ qkb, ushort* __restrict__ vtb,
    int M, int N, int K)
{
    __shared__ ushort Al[128 * 64];
    __shared__ ushort Bl[128 * 64];

    const int tid  = threadIdx.x;
    const int lane = tid & 63;
    const int wave = tid >> 6;
    const int wr   = wave >> 1;
    const int wc   = wave & 1;
    const int l15  = lane & 15;
    const int l4   = lane >> 4;

    // XCD-chunked bijective swizzle (gridDim.x % 8 == 0), N-major flat order
    const int nwg   = gridDim.x;
    const int chunk = nwg >> 3;
    const int f     = (blockIdx.x & 7) * chunk + (blockIdx.x >> 3);
    const int ny    = M >> 7;                 // M-tiles (fastest dim)
    const int m0    = (f % ny) * 128;
    const int n0    = (f / ny) * 128;

    f32x4 acc[4][4];
#pragma unroll
    for (int m = 0; m < 4; ++m)
#pragma unroll
        for (int n = 0; n < 4; ++n)
#pragma unroll
            for (int r = 0; r < 4; ++r) acc[m][n][r] = 0.f;

    for (int k0 = 0; k0 < K; k0 += 64) {
#pragma unroll
        for (int it = 0; it < 4; ++it) {
            int chunkc = tid + it * 256;
            int row = chunkc >> 3;
            int kc  = (chunkc & 7) * 8;
            gload_lds16(&A[(size_t)(m0 + row) * K + k0 + kc], &Al[chunkc * 8]);
            gload_lds16(&B[(size_t)(n0 + row) * K + k0 + kc], &Bl[chunkc * 8]);
        }
        __syncthreads();

#pragma unroll
        for (int kk = 0; kk < 2; ++kk) {
            const int ko = kk * 32 + l4 * 8;
            bf16x8 a[4], b[4];
#pragma unroll
            for (int m = 0; m < 4; ++m)
                a[m] = *reinterpret_cast<const bf16x8*>(
                    &Al[(wr * 64 + m * 16 + l15) * 64 + ko]);
#pragma unroll
            for (int n = 0; n < 4; ++n)
                b[n] = *reinterpret_cast<const bf16x8*>(
                    &Bl[(wc * 64 + n * 16 + l15) * 64 + ko]);
            __builtin_amdgcn_s_setprio(1);
#pragma unroll
            for (int m = 0; m < 4; ++m)
#pragma unroll
                for (int n = 0; n < 4; ++n)
                    acc[m][n] = __builtin_amdgcn_mfma_f32_16x16x32_bf16(
                        a[m], b[n], acc[m][n], 0, 0, 0);
            __builtin_amdgcn_s_setprio(0);
        }
        __syncthreads();
    }

    // epilogue; C/D: col = lane&15, row = (lane>>4)*4 + reg (verified)
#pragma unroll
    for (int n = 0; n < 4; ++n) {
        const int col = n0 + wc * 64 + n * 16 + l15;
        const float bv = bias[col];
        if (MODE == 0) {
#pragma unroll
            for (int m = 0; m < 4; ++m) {
                const int row0 = m0 + wr * 64 + m * 16 + l4 * 4;
#pragma unroll
                for (int r = 0; r < 4; ++r)
                    Cout[(size_t)(row0 + r) * N + col] = acc[m][n][r] + bv;
            }
        } else if (col < 2 * EMB) {
            // Q/K part, row-major bf16, stride 2048. Q pre-scaled by BETA.
            const float qs = (col < EMB) ? 0.18033688f : 1.0f;
#pragma unroll
            for (int m = 0; m < 4; ++m) {
                const int row0 = m0 + wr * 64 + m * 16 + l4 * 4;
#pragma unroll
                for (int r = 0; r < 4; ++r)
                    qkb[(size_t)(row0 + r) * 2048 + col] =
                        f2bf((acc[m][n][r] + bv) * qs);
            }
        } else {
            // V part, transposed: vtb[(b*16+h)*64 + d][t], t = row
            const int h = (col - 2 * EMB) >> 6;
            const int d = col & 63;
#pragma unroll
            for (int m = 0; m < 4; ++m) {
                const int row0 = m0 + wr * 64 + m * 16 + l4 * 4;
                const int bb = row0 >> 11;
                const int t  = row0 & 2047;
                uint2 pk;
                pk.x = cvt_pk_bf16(acc[m][n][0] + bv, acc[m][n][1] + bv);
                pk.y = cvt_pk_bf16(acc[m][n][2] + bv, acc[m][n][3] + bv);
                *reinterpret_cast<uint2*>(
                    &vtb[((size_t)(bb * 16 + h) * 64 + d) * 2048 + t]) = pk;
            }
        }
    }
}

// ---------------------------------------------------------------------------
// MFMA flash attention, swapped-QK softmax. UNIFORM-WORK blocks (best-known
// r10 structure): 512 threads (8 waves); block = (bh, pair p); processes
// q-tiles qt=p and qt=15-p SEQUENTIALLY -> exactly 34 kv-tile iterations per
// block. Grid 256 = 1 block/CU, no imbalance tail. Wave w owns q rows
// [w*16, w*16+16). QUAD-buffered K/V; 2 kv-tiles per barrier window.
// Q pre-scaled by BETA (log2-domain scores). Fully-masked-tile skip (w<4 on
// the pair's last tile). Lean softmax (per-lane partial max + ballot;
// l via MFMA-ones).
// ---------------------------------------------------------------------------
__global__ __launch_bounds__(512) void attn_mfma(
    const ushort* __restrict__ qk, const ushort* __restrict__ vt,
    ushort* __restrict__ y)
{
    __shared__ alignas(16) ushort Kl[4][4096];
    __shared__ alignas(16) ushort Vl[4][4096];
    __shared__ alignas(16) ushort QP[8192];     // 128 rows x 64

    const int tid  = threadIdx.x;
    const int lane = tid & 63;
    const int w    = tid >> 6;     // wave 0..7
    const int l15  = lane & 15;
    const int l4   = lane >> 4;

    // block -> (bh, pair): 4 consecutive bh per XCD
    const int id  = blockIdx.x;                   // 0..255
    const int xcd = id & 7;
    const int bh  = xcd * 4 + ((id >> 3) & 3);    // 0..31
    const int pp  = id >> 5;                      // pair 0..7
    const int b   = bh >> 4;
    const int h   = bh & 15;

    const ushort* qbase = qk + (size_t)b * SEQ * 2048 + h * HD;
    const ushort* kbase = qbase + EMB;
    const ushort* vbase = vt + (size_t)bh * HD * SEQ;        // [d][t]

    const int swz   = (l15 & 7) << 4;
    const int koff0 = ((l4 * 16) ^ swz) >> 1;        // ushort units
    const int koff1 = ((64 + l4 * 16) ^ swz) >> 1;

    int pso[4];
#pragma unroll
    for (int n = 0; n < 4; ++n) pso[n] = ((n * 32 + l4 * 8) ^ swz) >> 1;

    const short OBF = (short)0x3F80;   // 1.0 bf16
    const bf16x8 ones = {OBF, OBF, OBF, OBF, OBF, OBF, OBF, OBF};

    const int qrow = (w * 16 + l15) * 64;    // wave-local Q/P row base

    // staging coordinates (one 16B chunk per thread per 64x64 tile)
    const int sr = tid >> 3;                          // row 0..63
    const int sc = ((tid & 7) ^ (sr & 7)) << 3;       // swizzled col
    const int i2 = tid + 512;
    const int qr2 = i2 >> 3;
    const int qc2 = ((i2 & 7) ^ (qr2 & 7)) << 3;

#pragma unroll
    for (int pass = 0; pass < 2; ++pass) {
        const int qt  = pass ? (15 - pp) : pp;
        const int nkv = 2 * qt + 2;                   // even

        // ---- prologue: stage Q (128x64) + kv tiles 0,1 ----
        gload_lds16(qbase + (size_t)(qt * 128 + sr) * 2048 + sc, &QP[tid * 8]);
        gload_lds16(qbase + (size_t)(qt * 128 + qr2) * 2048 + qc2, &QP[i2 * 8]);
        gload_lds16(kbase + (size_t)sr * 2048 + sc, &Kl[0][tid * 8]);
        gload_lds16(kbase + (size_t)(64 + sr) * 2048 + sc, &Kl[1][tid * 8]);
        gload_lds16(vbase + (size_t)sr * 2048 + sc, &Vl[0][tid * 8]);
        gload_lds16(vbase + (size_t)sr * 2048 + 64 + sc, &Vl[1][tid * 8]);
        __syncthreads();

        const bf16x8 qf0 = *reinterpret_cast<const bf16x8*>(&QP[qrow + koff0]);
        const bf16x8 qf1 = *reinterpret_cast<const bf16x8*>(&QP[qrow + koff1]);

        f32x4 o[4];
#pragma unroll
        for (int n = 0; n < 4; ++n)
#pragma unroll
            for (int r = 0; r < 4; ++r) o[n][r] = 0.f;
        f32x4 lacc = {0.f, 0.f, 0.f, 0.f};
        float m = -3.0e38f;

        const int q0g = qt * 128 + w * 16 + l15;      // causal bound (this lane)

        auto computeTile = [&](const ushort* Kb, const ushort* Vb, int kkt) {
            bf16x8 kf[4][2];
#pragma unroll
            for (int n = 0; n < 4; ++n) {
                kf[n][0] = *reinterpret_cast<const bf16x8*>(
                    &Kb[(n * 16 + l15) * 64 + koff0]);
                kf[n][1] = *reinterpret_cast<const bf16x8*>(
                    &Kb[(n * 16 + l15) * 64 + koff1]);
            }
            f32x4 s[4];
            __builtin_amdgcn_s_setprio(1);
#pragma unroll
            for (int n = 0; n < 4; ++n) {
                f32x4 z = {0.f, 0.f, 0.f, 0.f};
                z = __builtin_amdgcn_mfma_f32_16x16x32_bf16(kf[n][0], qf0, z, 0, 0, 0);
                s[n] = __builtin_amdgcn_mfma_f32_16x16x32_bf16(kf[n][1], qf1, z, 0, 0, 0);
            }
            __builtin_amdgcn_s_setprio(0);

            bf16x8 vf[4][2];
#pragma unroll
            for (int n = 0; n < 4; ++n) {
                vf[n][0] = *reinterpret_cast<const bf16x8*>(
                    &Vb[(n * 16 + l15) * 64 + koff0]);
                vf[n][1] = *reinterpret_cast<const bf16x8*>(
                    &Vb[(n * 16 + l15) * 64 + koff1]);
            }

            // causal mask: only the last two kv tiles can violate causality
            if (kkt >= nkv - 2) {
#pragma unroll
                for (int n = 0; n < 4; ++n)
#pragma unroll
                    for (int r = 0; r < 4; ++r) {
                        int kg = kkt * 64 + n * 16 + l4 * 4 + r;
                        if (kg > q0g) s[n][r] = -3.0e38f;
                    }
            }

            // per-lane partial max (tree); scores already log2-domain
            float a0 = fmaxf(fmaxf(s[0][0], s[0][1]), fmaxf(s[0][2], s[0][3]));
            float a1 = fmaxf(fmaxf(s[1][0], s[1][1]), fmaxf(s[1][2], s[1][3]));
            float a2 = fmaxf(fmaxf(s[2][0], s[2][1]), fmaxf(s[2][2], s[2][3]));
            float a3 = fmaxf(fmaxf(s[3][0], s[3][1]), fmaxf(s[3][2], s[3][3]));
            float pm = fmaxf(fmaxf(a0, a1), fmaxf(a2, a3));

            // defer-max rescale (rare, wave-uniform); ballot covers all (k,q)
            if (__any(pm > m + 8.0f)) {
                float tm = fmaxf(pm, __shfl_xor(pm, 16));
                tm = fmaxf(tm, __shfl_xor(tm, 32));
                float mn = fmaxf(m, tm);
                float al = exp2f(m - mn);
                m = mn;
                float b0 = __shfl(al, l4 * 4 + 0, 16);
                float b1 = __shfl(al, l4 * 4 + 1, 16);
                float b2 = __shfl(al, l4 * 4 + 2, 16);
                float b3 = __shfl(al, l4 * 4 + 3, 16);
                lacc[0] *= b0; lacc[1] *= b1; lacc[2] *= b2; lacc[3] *= b3;
#pragma unroll
                for (int n = 0; n < 4; ++n) {
                    o[n][0] *= b0; o[n][1] *= b1; o[n][2] *= b2; o[n][3] *= b3;
                }
            }

            // p = 2^(s - m), pack + store P (wave-local rows)
#pragma unroll
            for (int n = 0; n < 4; ++n) {
                float pa = exp2f(s[n][0] - m);
                float pb = exp2f(s[n][1] - m);
                float pc = exp2f(s[n][2] - m);
                float pd = exp2f(s[n][3] - m);
                uint2 pk;
                pk.x = cvt_pk_bf16(pa, pb);
                pk.y = cvt_pk_bf16(pc, pd);
                *reinterpret_cast<uint2*>(&QP[qrow + pso[n]]) = pk;
            }

            // O += P V, l += P·1
            bf16x8 pf0 = *reinterpret_cast<const bf16x8*>(&QP[qrow + koff0]);
            bf16x8 pf1 = *reinterpret_cast<const bf16x8*>(&QP[qrow + koff1]);
            __builtin_amdgcn_s_setprio(1);
            lacc = __builtin_amdgcn_mfma_f32_16x16x32_bf16(pf0, ones, lacc, 0, 0, 0);
            lacc = __builtin_amdgcn_mfma_f32_16x16x32_bf16(pf1, ones, lacc, 0, 0, 0);
#pragma unroll
            for (int n = 0; n < 4; ++n) {
                o[n] = __builtin_amdgcn_mfma_f32_16x16x32_bf16(pf0, vf[n][0], o[n], 0, 0, 0);
                o[n] = __builtin_amdgcn_mfma_f32_16x16x32_bf16(pf1, vf[n][1], o[n], 0, 0, 0);
            }
            __builtin_amdgcn_s_setprio(0);
        };

        // ---- main loop: 2 tiles per barrier window ----
        for (int kk = 0; kk < nkv; kk += 2) {
            if (kk + 2 < nkv) {
                const int b2 = (kk + 2) & 3;
                const int b3 = (kk + 3) & 3;
                gload_lds16(kbase + (size_t)((kk + 2) * 64 + sr) * 2048 + sc,
                            &Kl[b2][tid * 8]);
                gload_lds16(kbase + (size_t)((kk + 3) * 64 + sr) * 2048 + sc,
                            &Kl[b3][tid * 8]);
                gload_lds16(vbase + (size_t)sr * 2048 + (kk + 2) * 64 + sc,
                            &Vl[b2][tid * 8]);
                gload_lds16(vbase + (size_t)sr * 2048 + (kk + 3) * 64 + sc,
                            &Vl[b3][tid * 8]);
            }
            computeTile(Kl[kk & 3], Vl[kk & 3], kk);
            // pair's last tile is fully masked for waves 0..3
            // (kv_start = 128qt+64 > q_max = 128qt+16w+15 when w < 4)
            if (!(kk == nkv - 2 && w < 4))
                computeTile(Kl[(kk + 1) & 3], Vl[(kk + 1) & 3], kk + 1);
            __syncthreads();
        }

        // epilogue: O rows q = w*16 + l4*4 + r, cols d = n*16 + l15
#pragma unroll
        for (int r = 0; r < 4; ++r) {
            float inv = 1.f / lacc[r];
            int row = qt * 128 + w * 16 + l4 * 4 + r;
#pragma unroll
            for (int n = 0; n < 4; ++n) {
                y[(size_t)(b * SEQ + row) * EMB + h * HD + n * 16 + l15] =
                    f2bf(o[n][r] * inv);
            }
        }
        __syncthreads();   // LDS safe before next pass's prologue
    }
}

// ---------------------------------------------------------------------------
extern "C" void kernel_launch(void* const* d_in, const int* in_sizes, int n_in,
                              void* d_out, int out_size, void* d_ws, size_t ws_size,
                              hipStream_t stream)
{
    const float* x     = (const float*)d_in[0];   // [B,T,E]
    const float* qkv_w = (const float*)d_in[1];   // [3E,E]
    const float* qkv_b = (const float*)d_in[2];   // [3E]
    const float* o_w   = (const float*)d_in[3];   // [E,E]
    const float* o_b   = (const float*)d_in[4];   // [E]
    float* out = (float*)d_out;                   // [B,T,E] fp32

    // workspace (ushort units)
    ushort* xb    = (ushort*)d_ws;                       // 4M
    ushort* wqkvb = xb    + (size_t)M_ROWS * EMB;        // 3M
    ushort* owb   = wqkvb + (size_t)3 * EMB * EMB;       // 1M
    ushort* qkb   = owb   + (size_t)EMB * EMB;           // 8M  [4096][2048]
    ushort* vtb   = qkb   + (size_t)M_ROWS * 2 * EMB;    // 4M  [32][64][2048]
    ushort* ybb   = vtb   + (size_t)32 * HD * SEQ;       // 4M  [4096][1024]

    // 0) fused fp32 -> bf16 (x, qkv_w, o_w -> contiguous xb/wqkvb/owb)
    {
        int n1 = M_ROWS * EMB;        // 4M
        int n2 = 3 * EMB * EMB;       // 3M
        int ntot = n1 + n2 + EMB * EMB;
        cvt3_f32_bf16<<<ntot / 1024, 256, 0, stream>>>(
            x, qkv_w, o_w, xb, n1, n2);
    }

    // 1) QKV projection (768 blocks, XCD-swizzled 1-D grid)
    {
        gemm_mfma_abt<1><<<768, 256, 0, stream>>>(
            xb, wqkvb, qkv_b, nullptr, qkb, vtb, M_ROWS, 3 * EMB, EMB);
    }

    // 2) MFMA flash attention -> ybb (bf16 [M,E]); uniform-work pair blocks
    {
        attn_mfma<<<256, 512, 0, stream>>>(qkb, vtb, ybb);
    }

    // 3) Output projection (256 blocks, XCD-swizzled 1-D grid)
    {
        gemm_mfma_abt<0><<<256, 256, 0, stream>>>(
            ybb, owb, o_b, out, nullptr, nullptr, M_ROWS, EMB, EMB);
    }
}

// Round 19
// 112.919 us; speedup vs baseline: 1.1331x; 1.0265x over previous
//
#include <hip/hip_runtime.h>
#include <hip/hip_bf16.h>
#include <math.h>

// Problem constants
#define BATCH 2
#define SEQ   2048
#define EMB   1024
#define NH    16
#define HD    64
#define M_ROWS (BATCH * SEQ)   // 4096

typedef __attribute__((ext_vector_type(8))) short bf16x8;
typedef __attribute__((ext_vector_type(4))) float f32x4;

// fp32 -> bf16 round-to-nearest-even, raw bits
__device__ __forceinline__ ushort f2bf(float f) {
    unsigned u = __float_as_uint(f);
    unsigned lsb = (u >> 16) & 1u;
    u += 0x7fffu + lsb;
    return (ushort)(u >> 16);
}

// packed f32 pair -> 2 bf16 in one u32 (RNE), single VALU op
__device__ __forceinline__ unsigned cvt_pk_bf16(float lo, float hi) {
    unsigned r;
    asm("v_cvt_pk_bf16_f32 %0, %1, %2" : "=v"(r) : "v"(lo), "v"(hi));
    return r;
}

__device__ __forceinline__ void gload_lds16(const void* g, void* l) {
    __builtin_amdgcn_global_load_lds(
        (const __attribute__((address_space(1))) unsigned int*)g,
        (__attribute__((address_space(3))) unsigned int*)l, 16, 0, 0);
}

// ---------------------------------------------------------------------------
// fused fp32 -> bf16 conversion of x, qkv_w, o_w (outputs contiguous in ws)
// ---------------------------------------------------------------------------
__global__ __launch_bounds__(256) void cvt3_f32_bf16(
    const float* __restrict__ s1, const float* __restrict__ s2,
    const float* __restrict__ s3, ushort* __restrict__ out,
    int n1, int n2)
{
    int i = (blockIdx.x * 256 + threadIdx.x) * 4;
    const float* src;
    int off;
    if (i < n1)            { src = s1; off = i; }
    else if (i < n1 + n2)  { src = s2; off = i - n1; }
    else                   { src = s3; off = i - n1 - n2; }
    float4 v = *reinterpret_cast<const float4*>(&src[off]);
    uint2 pk;
    pk.x = cvt_pk_bf16(v.x, v.y);
    pk.y = cvt_pk_bf16(v.z, v.w);
    *reinterpret_cast<uint2*>(&out[i]) = pk;
}

// ---------------------------------------------------------------------------
// bf16 MFMA GEMM: C[M,N] = A[M,K] * B[N,K]^T + bias[N]   (2-D grid, r11 form)
// MODE 0: fp32 output to Cout (O-projection).
// MODE 1: QKV split — cols [0,1024) = Q, scaled by BETA=0.125*log2(e);
//         cols [0,2048) bf16 to qkb (stride 2048), direct stores;
//         cols [2048,3072) = V written TRANSPOSED to vtb[b*16+h][d][t].
// ---------------------------------------------------------------------------
template <int MODE>
__global__ __launch_bounds__(256) void gemm_mfma_abt(
    const ushort* __restrict__ A, const ushort* __restrict__ B,
    const float* __restrict__ bias, float* __restrict__ Cout,
    ushort* __restrict__ qkb, ushort* __restrict__ vtb,
    int M, int N, int K)
{
    __shared__ ushort Al[128 * 64];
    __shared__ ushort Bl[128 * 64];

    const int tid  = threadIdx.x;
    const int lane = tid & 63;
    const int wave = tid >> 6;
    const int wr   = wave >> 1;
    const int wc   = wave & 1;
    const int l15  = lane & 15;
    const int l4   = lane >> 4;
    const int m0   = blockIdx.y * 128;
    const int n0   = blockIdx.x * 128;

    f32x4 acc[4][4];
#pragma unroll
    for (int m = 0; m < 4; ++m)
#pragma unroll
        for (int n = 0; n < 4; ++n)
#pragma unroll
            for (int r = 0; r < 4; ++r) acc[m][n][r] = 0.f;

    for (int k0 = 0; k0 < K; k0 += 64) {
#pragma unroll
        for (int it = 0; it < 4; ++it) {
            int chunk = tid + it * 256;
            int row = chunk >> 3;
            int kc  = (chunk & 7) * 8;
            gload_lds16(&A[(size_t)(m0 + row) * K + k0 + kc], &Al[chunk * 8]);
            gload_lds16(&B[(size_t)(n0 + row) * K + k0 + kc], &Bl[chunk * 8]);
        }
        __syncthreads();

#pragma unroll
        for (int kk = 0; kk < 2; ++kk) {
            const int ko = kk * 32 + l4 * 8;
            bf16x8 a[4], b[4];
#pragma unroll
            for (int m = 0; m < 4; ++m)
                a[m] = *reinterpret_cast<const bf16x8*>(
                    &Al[(wr * 64 + m * 16 + l15) * 64 + ko]);
#pragma unroll
            for (int n = 0; n < 4; ++n)
                b[n] = *reinterpret_cast<const bf16x8*>(
                    &Bl[(wc * 64 + n * 16 + l15) * 64 + ko]);
            __builtin_amdgcn_s_setprio(1);
#pragma unroll
            for (int m = 0; m < 4; ++m)
#pragma unroll
                for (int n = 0; n < 4; ++n)
                    acc[m][n] = __builtin_amdgcn_mfma_f32_16x16x32_bf16(
                        a[m], b[n], acc[m][n], 0, 0, 0);
            __builtin_amdgcn_s_setprio(0);
        }
        __syncthreads();
    }

    // epilogue; C/D: col = lane&15, row = (lane>>4)*4 + reg (verified)
#pragma unroll
    for (int n = 0; n < 4; ++n) {
        const int col = n0 + wc * 64 + n * 16 + l15;
        const float bv = bias[col];
        if (MODE == 0) {
#pragma unroll
            for (int m = 0; m < 4; ++m) {
                const int row0 = m0 + wr * 64 + m * 16 + l4 * 4;
#pragma unroll
                for (int r = 0; r < 4; ++r)
                    Cout[(size_t)(row0 + r) * N + col] = acc[m][n][r] + bv;
            }
        } else if (col < 2 * EMB) {
            // Q/K part, row-major bf16, stride 2048. Q pre-scaled by BETA.
            const float qs = (col < EMB) ? 0.18033688f : 1.0f;
#pragma unroll
            for (int m = 0; m < 4; ++m) {
                const int row0 = m0 + wr * 64 + m * 16 + l4 * 4;
#pragma unroll
                for (int r = 0; r < 4; ++r)
                    qkb[(size_t)(row0 + r) * 2048 + col] =
                        f2bf((acc[m][n][r] + bv) * qs);
            }
        } else {
            // V part, transposed: vtb[(b*16+h)*64 + d][t], t = row
            const int h = (col - 2 * EMB) >> 6;
            const int d = col & 63;
#pragma unroll
            for (int m = 0; m < 4; ++m) {
                const int row0 = m0 + wr * 64 + m * 16 + l4 * 4;
                const int bb = row0 >> 11;
                const int t  = row0 & 2047;
                uint2 pk;
                pk.x = cvt_pk_bf16(acc[m][n][0] + bv, acc[m][n][1] + bv);
                pk.y = cvt_pk_bf16(acc[m][n][2] + bv, acc[m][n][3] + bv);
                *reinterpret_cast<uint2*>(
                    &vtb[((size_t)(bb * 16 + h) * 64 + d) * 2048 + t]) = pk;
            }
        }
    }
}

// ---------------------------------------------------------------------------
// MFMA flash attention, swapped-QK softmax. UNIFORM-WORK blocks (best-known
// r11 structure): 512 threads (8 waves); block = (bh, pair p); processes
// q-tiles qt=p and qt=15-p SEQUENTIALLY -> exactly 34 kv-tile iterations per
// block. Grid 256 = 1 block/CU, no imbalance tail. Wave w owns q rows
// [w*16, w*16+16). QUAD-buffered K/V; 2 kv-tiles per barrier window.
// Q pre-scaled by BETA (log2-domain scores). Fully-masked-tile skip (w<4 on
// the pair's last tile). Lean softmax (per-lane partial max + ballot;
// l via MFMA-ones).
// ---------------------------------------------------------------------------
__global__ __launch_bounds__(512) void attn_mfma(
    const ushort* __restrict__ qk, const ushort* __restrict__ vt,
    ushort* __restrict__ y)
{
    __shared__ alignas(16) ushort Kl[4][4096];
    __shared__ alignas(16) ushort Vl[4][4096];
    __shared__ alignas(16) ushort QP[8192];     // 128 rows x 64

    const int tid  = threadIdx.x;
    const int lane = tid & 63;
    const int w    = tid >> 6;     // wave 0..7
    const int l15  = lane & 15;
    const int l4   = lane >> 4;

    // block -> (bh, pair): 4 consecutive bh per XCD
    const int id  = blockIdx.x;                   // 0..255
    const int xcd = id & 7;
    const int bh  = xcd * 4 + ((id >> 3) & 3);    // 0..31
    const int pp  = id >> 5;                      // pair 0..7
    const int b   = bh >> 4;
    const int h   = bh & 15;

    const ushort* qbase = qk + (size_t)b * SEQ * 2048 + h * HD;
    const ushort* kbase = qbase + EMB;
    const ushort* vbase = vt + (size_t)bh * HD * SEQ;        // [d][t]

    const int swz   = (l15 & 7) << 4;
    const int koff0 = ((l4 * 16) ^ swz) >> 1;        // ushort units
    const int koff1 = ((64 + l4 * 16) ^ swz) >> 1;

    int pso[4];
#pragma unroll
    for (int n = 0; n < 4; ++n) pso[n] = ((n * 32 + l4 * 8) ^ swz) >> 1;

    const short OBF = (short)0x3F80;   // 1.0 bf16
    const bf16x8 ones = {OBF, OBF, OBF, OBF, OBF, OBF, OBF, OBF};

    const int qrow = (w * 16 + l15) * 64;    // wave-local Q/P row base

    // staging coordinates (one 16B chunk per thread per 64x64 tile)
    const int sr = tid >> 3;                          // row 0..63
    const int sc = ((tid & 7) ^ (sr & 7)) << 3;       // swizzled col
    const int i2 = tid + 512;
    const int qr2 = i2 >> 3;
    const int qc2 = ((i2 & 7) ^ (qr2 & 7)) << 3;

#pragma unroll
    for (int pass = 0; pass < 2; ++pass) {
        const int qt  = pass ? (15 - pp) : pp;
        const int nkv = 2 * qt + 2;                   // even

        // ---- prologue: stage Q (128x64) + kv tiles 0,1 ----
        gload_lds16(qbase + (size_t)(qt * 128 + sr) * 2048 + sc, &QP[tid * 8]);
        gload_lds16(qbase + (size_t)(qt * 128 + qr2) * 2048 + qc2, &QP[i2 * 8]);
        gload_lds16(kbase + (size_t)sr * 2048 + sc, &Kl[0][tid * 8]);
        gload_lds16(kbase + (size_t)(64 + sr) * 2048 + sc, &Kl[1][tid * 8]);
        gload_lds16(vbase + (size_t)sr * 2048 + sc, &Vl[0][tid * 8]);
        gload_lds16(vbase + (size_t)sr * 2048 + 64 + sc, &Vl[1][tid * 8]);
        __syncthreads();

        const bf16x8 qf0 = *reinterpret_cast<const bf16x8*>(&QP[qrow + koff0]);
        const bf16x8 qf1 = *reinterpret_cast<const bf16x8*>(&QP[qrow + koff1]);

        f32x4 o[4];
#pragma unroll
        for (int n = 0; n < 4; ++n)
#pragma unroll
            for (int r = 0; r < 4; ++r) o[n][r] = 0.f;
        f32x4 lacc = {0.f, 0.f, 0.f, 0.f};
        float m = -3.0e38f;

        const int q0g = qt * 128 + w * 16 + l15;      // causal bound (this lane)

        auto computeTile = [&](const ushort* Kb, const ushort* Vb, int kkt) {
            bf16x8 kf[4][2];
#pragma unroll
            for (int n = 0; n < 4; ++n) {
                kf[n][0] = *reinterpret_cast<const bf16x8*>(
                    &Kb[(n * 16 + l15) * 64 + koff0]);
                kf[n][1] = *reinterpret_cast<const bf16x8*>(
                    &Kb[(n * 16 + l15) * 64 + koff1]);
            }
            f32x4 s[4];
            __builtin_amdgcn_s_setprio(1);
#pragma unroll
            for (int n = 0; n < 4; ++n) {
                f32x4 z = {0.f, 0.f, 0.f, 0.f};
                z = __builtin_amdgcn_mfma_f32_16x16x32_bf16(kf[n][0], qf0, z, 0, 0, 0);
                s[n] = __builtin_amdgcn_mfma_f32_16x16x32_bf16(kf[n][1], qf1, z, 0, 0, 0);
            }
            __builtin_amdgcn_s_setprio(0);

            bf16x8 vf[4][2];
#pragma unroll
            for (int n = 0; n < 4; ++n) {
                vf[n][0] = *reinterpret_cast<const bf16x8*>(
                    &Vb[(n * 16 + l15) * 64 + koff0]);
                vf[n][1] = *reinterpret_cast<const bf16x8*>(
                    &Vb[(n * 16 + l15) * 64 + koff1]);
            }

            // causal mask: only the last two kv tiles can violate causality
            if (kkt >= nkv - 2) {
#pragma unroll
                for (int n = 0; n < 4; ++n)
#pragma unroll
                    for (int r = 0; r < 4; ++r) {
                        int kg = kkt * 64 + n * 16 + l4 * 4 + r;
                        if (kg > q0g) s[n][r] = -3.0e38f;
                    }
            }

            // per-lane partial max (tree); scores already log2-domain
            float a0 = fmaxf(fmaxf(s[0][0], s[0][1]), fmaxf(s[0][2], s[0][3]));
            float a1 = fmaxf(fmaxf(s[1][0], s[1][1]), fmaxf(s[1][2], s[1][3]));
            float a2 = fmaxf(fmaxf(s[2][0], s[2][1]), fmaxf(s[2][2], s[2][3]));
            float a3 = fmaxf(fmaxf(s[3][0], s[3][1]), fmaxf(s[3][2], s[3][3]));
            float pm = fmaxf(fmaxf(a0, a1), fmaxf(a2, a3));

            // defer-max rescale (rare, wave-uniform); ballot covers all (k,q)
            if (__any(pm > m + 8.0f)) {
                float tm = fmaxf(pm, __shfl_xor(pm, 16));
                tm = fmaxf(tm, __shfl_xor(tm, 32));
                float mn = fmaxf(m, tm);
                float al = exp2f(m - mn);
                m = mn;
                float b0 = __shfl(al, l4 * 4 + 0, 16);
                float b1 = __shfl(al, l4 * 4 + 1, 16);
                float b2 = __shfl(al, l4 * 4 + 2, 16);
                float b3 = __shfl(al, l4 * 4 + 3, 16);
                lacc[0] *= b0; lacc[1] *= b1; lacc[2] *= b2; lacc[3] *= b3;
#pragma unroll
                for (int n = 0; n < 4; ++n) {
                    o[n][0] *= b0; o[n][1] *= b1; o[n][2] *= b2; o[n][3] *= b3;
                }
            }

            // p = 2^(s - m), pack + store P (wave-local rows)
#pragma unroll
            for (int n = 0; n < 4; ++n) {
                float pa = exp2f(s[n][0] - m);
                float pb = exp2f(s[n][1] - m);
                float pc = exp2f(s[n][2] - m);
                float pd = exp2f(s[n][3] - m);
                uint2 pk;
                pk.x = cvt_pk_bf16(pa, pb);
                pk.y = cvt_pk_bf16(pc, pd);
                *reinterpret_cast<uint2*>(&QP[qrow + pso[n]]) = pk;
            }

            // O += P V, l += P·1
            bf16x8 pf0 = *reinterpret_cast<const bf16x8*>(&QP[qrow + koff0]);
            bf16x8 pf1 = *reinterpret_cast<const bf16x8*>(&QP[qrow + koff1]);
            __builtin_amdgcn_s_setprio(1);
            lacc = __builtin_amdgcn_mfma_f32_16x16x32_bf16(pf0, ones, lacc, 0, 0, 0);
            lacc = __builtin_amdgcn_mfma_f32_16x16x32_bf16(pf1, ones, lacc, 0, 0, 0);
#pragma unroll
            for (int n = 0; n < 4; ++n) {
                o[n] = __builtin_amdgcn_mfma_f32_16x16x32_bf16(pf0, vf[n][0], o[n], 0, 0, 0);
                o[n] = __builtin_amdgcn_mfma_f32_16x16x32_bf16(pf1, vf[n][1], o[n], 0, 0, 0);
            }
            __builtin_amdgcn_s_setprio(0);
        };

        // ---- main loop: 2 tiles per barrier window ----
        for (int kk = 0; kk < nkv; kk += 2) {
            if (kk + 2 < nkv) {
                const int b2 = (kk + 2) & 3;
                const int b3 = (kk + 3) & 3;
                gload_lds16(kbase + (size_t)((kk + 2) * 64 + sr) * 2048 + sc,
                            &Kl[b2][tid * 8]);
                gload_lds16(kbase + (size_t)((kk + 3) * 64 + sr) * 2048 + sc,
                            &Kl[b3][tid * 8]);
                gload_lds16(vbase + (size_t)sr * 2048 + (kk + 2) * 64 + sc,
                            &Vl[b2][tid * 8]);
                gload_lds16(vbase + (size_t)sr * 2048 + (kk + 3) * 64 + sc,
                            &Vl[b3][tid * 8]);
            }
            computeTile(Kl[kk & 3], Vl[kk & 3], kk);
            // pair's last tile is fully masked for waves 0..3
            // (kv_start = 128qt+64 > q_max = 128qt+16w+15 when w < 4)
            if (!(kk == nkv - 2 && w < 4))
                computeTile(Kl[(kk + 1) & 3], Vl[(kk + 1) & 3], kk + 1);
            __syncthreads();
        }

        // epilogue: O rows q = w*16 + l4*4 + r, cols d = n*16 + l15
#pragma unroll
        for (int r = 0; r < 4; ++r) {
            float inv = 1.f / lacc[r];
            int row = qt * 128 + w * 16 + l4 * 4 + r;
#pragma unroll
            for (int n = 0; n < 4; ++n) {
                y[(size_t)(b * SEQ + row) * EMB + h * HD + n * 16 + l15] =
                    f2bf(o[n][r] * inv);
            }
        }
        __syncthreads();   // LDS safe before next pass's prologue
    }
}

// ---------------------------------------------------------------------------
extern "C" void kernel_launch(void* const* d_in, const int* in_sizes, int n_in,
                              void* d_out, int out_size, void* d_ws, size_t ws_size,
                              hipStream_t stream)
{
    const float* x     = (const float*)d_in[0];   // [B,T,E]
    const float* qkv_w = (const float*)d_in[1];   // [3E,E]
    const float* qkv_b = (const float*)d_in[2];   // [3E]
    const float* o_w   = (const float*)d_in[3];   // [E,E]
    const float* o_b   = (const float*)d_in[4];   // [E]
    float* out = (float*)d_out;                   // [B,T,E] fp32

    // workspace (ushort units)
    ushort* xb    = (ushort*)d_ws;                       // 4M
    ushort* wqkvb = xb    + (size_t)M_ROWS * EMB;        // 3M
    ushort* owb   = wqkvb + (size_t)3 * EMB * EMB;       // 1M
    ushort* qkb   = owb   + (size_t)EMB * EMB;           // 8M  [4096][2048]
    ushort* vtb   = qkb   + (size_t)M_ROWS * 2 * EMB;    // 4M  [32][64][2048]
    ushort* ybb   = vtb   + (size_t)32 * HD * SEQ;       // 4M  [4096][1024]

    // 0) fused fp32 -> bf16 (x, qkv_w, o_w -> contiguous xb/wqkvb/owb)
    {
        int n1 = M_ROWS * EMB;        // 4M
        int n2 = 3 * EMB * EMB;       // 3M
        int ntot = n1 + n2 + EMB * EMB;
        cvt3_f32_bf16<<<ntot / 1024, 256, 0, stream>>>(
            x, qkv_w, o_w, xb, n1, n2);
    }

    // 1) QKV projection, split output: Q (BETA-scaled)/K row-major, V transposed
    {
        dim3 grid(3 * EMB / 128, M_ROWS / 128);   // (24, 32)
        gemm_mfma_abt<1><<<grid, 256, 0, stream>>>(
            xb, wqkvb, qkv_b, nullptr, qkb, vtb, M_ROWS, 3 * EMB, EMB);
    }

    // 2) MFMA flash attention -> ybb (bf16 [M,E]); uniform-work pair blocks
    {
        attn_mfma<<<256, 512, 0, stream>>>(qkb, vtb, ybb);
    }

    // 3) Output projection (fp32 out)
    {
        dim3 grid(EMB / 128, M_ROWS / 128);       // (8, 32)
        gemm_mfma_abt<0><<<grid, 256, 0, stream>>>(
            ybb, owb, o_b, out, nullptr, nullptr, M_ROWS, EMB, EMB);
    }
}